// Round 15
// baseline (51.482 us; speedup 1.0000x reference)
//
#include <hip/hip_runtime.h>

#define W 512
#define H 512
#define OWID 506
#define OHT 506
#define BC 48              // 16 images * 3 channels
#define SEGOUT 24          // output cols per 16-lane segment (2/lane, q<=11)
#define WAVEOUT 96         // 4 segments
#define NSTRIP 6           // 6*96 = 576 >= 506
#define CH 28              // output rows per chunk (4 groups of 7)
#define NCHUNK 19          // 19*28 = 532 >= 506
#define NWAVE (BC*NSTRIP*NCHUNK)   // 5472, divisible by 4
#define NPIX 12289728.0f           // 16*3*506*506
#define DEPTH 8            // LDS FIFO slots per wave (1 KB each)

__device__ __forceinline__ float clip01(float v) { return fminf(fmaxf(v, 0.f), 1.f); }

// async DMA: 64 lanes x 16 B -> LDS slot (lane i writes bytes 16i..16i+15).
// Global src is PER-LANE; LDS dest is wave-uniform base.
__device__ __forceinline__ void stage_row(const float* gp, float* ls) {
    __builtin_amdgcn_global_load_lds(
        (const __attribute__((address_space(1))) unsigned int*)gp,
        (__attribute__((address_space(3))) unsigned int*)ls,
        16, 0, 0);
}
#define VMWAIT7() asm volatile("s_waitcnt vmcnt(7)" ::: "memory")
#define VMWAIT0() asm volatile("s_waitcnt vmcnt(0)" ::: "memory")
#define LGWAIT0() asm volatile("s_waitcnt lgkmcnt(0)" ::: "memory")

// DPP row_shl:N — lane p receives lane p+N within its 16-lane row; 0 if OOB.
template <int N>
__device__ __forceinline__ float dpp_shl(float v) {
    int r = __builtin_amdgcn_update_dpp(0, __float_as_int(v),
                                        0x100 + N, 0xF, 0xF, true);
    return __int_as_float(r);
}

// V = (even-col sum, odd-col sum). Returns (h for col 2q, h for col 2q+1).
__device__ __forceinline__ float2 hpair(float2 V) {
    float P  = V.x + V.y;
    float S2 = P + dpp_shl<1>(P);
    float S4 = S2 + dpp_shl<2>(S2);
    float2 h;
    h.x = S4 - dpp_shl<3>(V.y);
    h.y = S4 - V.x;
    return h;
}

// sum-domain SSIM (scaled by 49^4)
__device__ __forceinline__ float ssim_v(float a0, float a1, float az, float a4) {
    const float c1p   = 0.2401f;        // C1 * 49^2
    const float c2p   = 2.1609f;        // C2 * 49^2
    const float covn  = 49.0f / 48.0f;
    const float covn2 = 49.0f / 24.0f;
    float t01  = a0 * a1;
    float qs   = fmaf(a0, a0, a1 * a1);
    float w4   = fmaf(49.f, a4, -t01);
    float num1 = fmaf(2.f, t01, c1p);
    float num2 = fmaf(covn2, w4, c2p);
    float w23  = fmaf(49.f, az, -qs);
    float den1 = qs + c1p;
    float den2 = fmaf(covn, w23, c2p);
    return (num1 * num2) * __builtin_amdgcn_rcpf(den1 * den2);
}

__global__ __launch_bounds__(256)
void ssim_stream(const float* __restrict__ pred, const float* __restrict__ targ,
                 float* __restrict__ partial, float* __restrict__ out_atomic)
{
    // per-wave private FIFO: 8 slots x 256 floats (512 B x | 512 B y)
    __shared__ float lds[4][DEPTH][256];

    const int w    = threadIdx.x >> 6;
    const int wid  = __builtin_amdgcn_readfirstlane(blockIdx.x * 4 + w);
    const int lane = threadIdx.x & 63;
    const int sg   = lane >> 4;        // segment 0..3 (consume side)
    const int q    = lane & 15;

    const int bc    = wid / (NSTRIP * NCHUNK);
    const int rem   = wid - bc * (NSTRIP * NCHUNK);
    const int strip = rem / NCHUNK;
    const int chunk = rem - strip * NCHUNK;

    const int cbase = strip * WAVEOUT;
    const int ce  = cbase + sg * SEGOUT + 2 * q;   // even output col this lane owns
    const bool oke = (q <= 11) && (ce     < OWID);
    const bool oko = (q <= 11) && (ce + 1 < OWID);

    const int oy0 = chunk * CH;
    const size_t bb = (size_t)bc * (H * W);

    // staging lane -> global col: lane i<32 stages pred, i>=32 stages targ.
    // chunk layout: x floats f=4i..4i+3 -> seg i/8 (stride 24 cols), col 4*(i%8).
    const int li     = lane & 31;
    const int colrel = 24 * (li >> 3) + 4 * (li & 7);       // 16B-aligned
    const int gcol   = min(cbase + colrel, W - 4);          // clamp (strip 5 tail)
    const float* gp  = ((lane < 32) ? pred : targ) + bb + (size_t)oy0 * W + gcol;
    int rnext = oy0;   // row gp currently points at (virtual; gp clamps at H-1)

    // ---- prologue: fill FIFO with rows oy0..oy0+7 (all <= 511) ----
    #pragma unroll
    for (int r = 0; r < DEPTH; ++r) {
        stage_row(gp, &lds[w][r][0]);
        if (rnext < H - 1) gp += W;    // scalar-guarded per-lane advance
        ++rnext;
    }

    // ---- init-consume rows 0..6, refill with rows 8..14 ----
    float2 ringx[7], ringy[7];
    float2 Vx = {0,0}, Vy = {0,0}, Vz = {0,0}, Vxy = {0,0};
    #pragma unroll
    for (int i = 0; i < 7; ++i) {
        VMWAIT7();                                  // oldest slot (row i) landed
        __builtin_amdgcn_sched_barrier(0);
        float2 xr = *(const float2*)&lds[w][i][      32 * sg + 2 * q];
        float2 yr = *(const float2*)&lds[w][i][128 + 32 * sg + 2 * q];
        LGWAIT0();                                  // reads retired before overwrite
        stage_row(gp, &lds[w][i][0]);               // issue row i+8 into slot i
        if (rnext < H - 1) gp += W;
        ++rnext;
        float2 x, y;
        x.x = clip01(xr.x); x.y = clip01(xr.y);
        y.x = clip01(yr.x); y.y = clip01(yr.y);
        ringx[i] = x; ringy[i] = y;
        Vx.x += x.x; Vx.y += x.y;
        Vy.x += y.x; Vy.y += y.y;
        Vz.x  = fmaf(x.x, x.x, Vz.x);  Vz.x  = fmaf(y.x, y.x, Vz.x);
        Vz.y  = fmaf(x.y, x.y, Vz.y);  Vz.y  = fmaf(y.y, y.y, Vz.y);
        Vxy.x = fmaf(x.x, y.x, Vxy.x);
        Vxy.y = fmaf(x.y, y.y, Vxy.y);
    }

    int slot = DEPTH - 1;   // row 7 lives in slot 7; then 8->0, 9->1, ... (scalar)
    float acc = 0.f;

    #pragma unroll 1
    for (int g = 0; g < 4; ++g) {
        if (oy0 + 7 * g >= OHT) break;     // scalar early-exit (last chunk)
        #pragma unroll
        for (int i = 0; i < 7; ++i) {      // t = 7g+i; reg-ring slot i static
            const int t = g * 7 + i;
            // ---- emit output row oy0+t ----
            {
                float2 hx = hpair(Vx);
                float2 hy = hpair(Vy);
                float2 hz = hpair(Vz);
                float2 hw = hpair(Vxy);
                float ve = ssim_v(hx.x, hy.x, hz.x, hw.x);
                float vo = ssim_v(hx.y, hy.y, hz.y, hw.y);
                bool rok = (oy0 + t) < OHT;          // scalar
                acc += (oke && rok) ? ve : 0.f;
                acc += (oko && rok) ? vo : 0.f;
            }
            // ---- consume incoming row t+7 from FIFO, reissue row t+15 ----
            {
                float* sp = &lds[w][slot][0];        // slot is wave-uniform
                VMWAIT7();
                __builtin_amdgcn_sched_barrier(0);
                float2 xr = *(const float2*)(sp +       32 * sg + 2 * q);
                float2 yr = *(const float2*)(sp + 128 + 32 * sg + 2 * q);
                LGWAIT0();
                stage_row(gp, sp);                   // row t+15 (clamped)
                if (rnext < H - 1) gp += W;
                ++rnext;
                slot = (slot + 1) & (DEPTH - 1);
                float2 xo = ringx[i], yo = ringy[i];
                float2 xn, yn;
                xn.x = clip01(xr.x); xn.y = clip01(xr.y);
                yn.x = clip01(yr.x); yn.y = clip01(yr.y);
                Vx.x += xn.x - xo.x;  Vx.y += xn.y - xo.y;
                Vy.x += yn.x - yo.x;  Vy.y += yn.y - yo.y;
                float zne = fmaf(xn.x, xn.x, yn.x * yn.x);
                float zoe = fmaf(xo.x, xo.x, yo.x * yo.x);
                float zno = fmaf(xn.y, xn.y, yn.y * yn.y);
                float zoo = fmaf(xo.y, xo.y, yo.y * yo.y);
                Vz.x += zne - zoe;    Vz.y += zno - zoo;
                Vxy.x += fmaf(xn.x, yn.x, -(xo.x * yo.x));
                Vxy.y += fmaf(xn.y, yn.y, -(xo.y * yo.y));
                ringx[i] = xn; ringy[i] = yn;
            }
        }
    }

    VMWAIT0();   // drain outstanding DMA before exit/stores

    // ---- wave reduction, one partial per wave ----
    #pragma unroll
    for (int off = 32; off >= 1; off >>= 1)
        acc += __shfl_down(acc, off, 64);
    if (lane == 0) {
        if (partial) partial[wid] = acc;
        else atomicAdd(out_atomic, acc);
    }
}

__global__ __launch_bounds__(256)
void ssim_finish(const float* __restrict__ partial, float* __restrict__ out)
{
    __shared__ float red[4];
    float s = 0.f;
    for (int i = threadIdx.x; i < NWAVE; i += 256) s += partial[i];
    #pragma unroll
    for (int off = 32; off >= 1; off >>= 1)
        s += __shfl_down(s, off, 64);
    if ((threadIdx.x & 63) == 0) red[threadIdx.x >> 6] = s;
    __syncthreads();
    if (threadIdx.x == 0) {
        float t = red[0] + red[1] + red[2] + red[3];
        out[0] = 1.0f - t / NPIX;
    }
}

__global__ void ssim_zero(float* out) { out[0] = 0.0f; }
__global__ void ssim_finish_atomic(float* out) { out[0] = 1.0f - out[0] / NPIX; }

extern "C" void kernel_launch(void* const* d_in, const int* in_sizes, int n_in,
                              void* d_out, int out_size, void* d_ws, size_t ws_size,
                              hipStream_t stream) {
    const float* pred = (const float*)d_in[0];
    const float* targ = (const float*)d_in[1];
    float* out = (float*)d_out;

    dim3 block(256);
    dim3 grid(NWAVE / 4);   // 1368 blocks, 4 waves each

    if (ws_size >= (size_t)NWAVE * sizeof(float)) {
        float* part = (float*)d_ws;
        ssim_stream<<<grid, block, 0, stream>>>(pred, targ, part, nullptr);
        ssim_finish<<<1, 256, 0, stream>>>(part, out);
    } else {
        ssim_zero<<<1, 1, 0, stream>>>(out);
        ssim_stream<<<grid, block, 0, stream>>>(pred, targ, nullptr, out);
        ssim_finish_atomic<<<1, 1, 0, stream>>>(out);
    }
}

// Round 16
// 38.260 us; speedup vs baseline: 1.3456x; 1.3456x over previous
//
#include <hip/hip_runtime.h>

#define W 512
#define H 512
#define OWID 506
#define OHT 506
#define BC 48              // 16 images * 3 channels
#define SEGOUT 26          // valid output cols per 16-lane segment (2/lane, q<=12)
#define WAVEOUT 104        // 4 segments
#define NSTRIP 5           // 5*104 = 520 >= 506
#define CH 21              // output rows per chunk (3 groups of 7)
#define NCHUNK 25          // 25*21 = 525 >= 506
#define NWAVE (BC*NSTRIP*NCHUNK)   // 6000, divisible by 4
#define NPIX 12289728.0f           // 16*3*506*506

__device__ __forceinline__ float clip01(float v) { return fminf(fmaxf(v, 0.f), 1.f); }

// DPP row_shl:N — lane p receives lane p+N within its 16-lane row; 0 if OOB.
template <int N>
__device__ __forceinline__ float dpp_shl(float v) {
    int r = __builtin_amdgcn_update_dpp(0, __float_as_int(v),
                                        0x100 + N, 0xF, 0xF, true);
    return __int_as_float(r);
}

// V = (even-col sum, odd-col sum). Returns (h for col 2q, h for col 2q+1).
// P=Ve+Vo; S4 = 8-col sum (lanes q..q+3); h_e = S4 - col(2q+7); h_o = S4 - col(2q).
__device__ __forceinline__ float2 hpair(float2 V) {
    float P  = V.x + V.y;
    float S2 = P + dpp_shl<1>(P);
    float S4 = S2 + dpp_shl<2>(S2);
    float2 h;
    h.x = S4 - dpp_shl<3>(V.y);
    h.y = S4 - V.x;
    return h;
}

// sum-domain SSIM (scaled by 49^4)
__device__ __forceinline__ float ssim_v(float a0, float a1, float az, float a4) {
    const float c1p   = 0.2401f;        // C1 * 49^2
    const float c2p   = 2.1609f;        // C2 * 49^2
    const float covn  = 49.0f / 48.0f;
    const float covn2 = 49.0f / 24.0f;
    float t01  = a0 * a1;
    float qs   = fmaf(a0, a0, a1 * a1);
    float w4   = fmaf(49.f, a4, -t01);
    float num1 = fmaf(2.f, t01, c1p);
    float num2 = fmaf(covn2, w4, c2p);
    float w23  = fmaf(49.f, az, -qs);
    float den1 = qs + c1p;
    float den2 = fmaf(covn, w23, c2p);
    return (num1 * num2) * __builtin_amdgcn_rcpf(den1 * den2);
}

__global__ __launch_bounds__(256)
void ssim_stream(const float* __restrict__ pred, const float* __restrict__ targ,
                 float* __restrict__ partial, float* __restrict__ out_atomic)
{
    // wave-uniform id -> SGPR addressing, scalar row pointers
    const int wid  = __builtin_amdgcn_readfirstlane(blockIdx.x * 4 + (threadIdx.x >> 6));
    const int lane = threadIdx.x & 63;
    const int seg  = lane >> 4;
    const int q    = lane & 15;

    // STRIP-FASTEST decomposition: co-dispatched waves = the 5 strips of the
    // same (image, row-chunk) -> device-wide reads form contiguous 2KB rows.
    const int bc    = wid / (NSTRIP * NCHUNK);
    const int rem   = wid - bc * (NSTRIP * NCHUNK);
    const int chunk = rem / NSTRIP;
    const int strip = rem - chunk * NSTRIP;

    const int ce = strip * WAVEOUT + seg * SEGOUT + 2 * q;  // even col this lane owns
    const int co = min(ce, W - 2);                          // clamped float2 col
    const bool oke = (q <= 12) && (ce     < OWID);
    const bool oko = (q <= 12) && (ce + 1 < OWID);

    const int oy0 = chunk * CH;
    const size_t base = (size_t)bc * (H * W) + (size_t)oy0 * W;
    const float* __restrict__ px = pred + base;   // scalar base, row oy0
    const float* __restrict__ py = targ + base;

    // ---- vertical-first state: ring of clipped pairs, running pair sums ----
    float2 ringx[7], ringy[7];
    float2 Vx = {0,0}, Vy = {0,0}, Vz = {0,0}, Vxy = {0,0};

    float2 nx = *(const float2*)(px + co);
    float2 ny = *(const float2*)(py + co);
    #pragma unroll
    for (int i = 0; i < 7; ++i) {
        float2 xr = nx, yr = ny;
        nx = *(const float2*)(px + (i + 1) * W + co);   // rows 1..7 (<=511)
        ny = *(const float2*)(py + (i + 1) * W + co);
        float2 x, y;
        x.x = clip01(xr.x); x.y = clip01(xr.y);
        y.x = clip01(yr.x); y.y = clip01(yr.y);
        ringx[i] = x; ringy[i] = y;
        Vx.x += x.x; Vx.y += x.y;
        Vy.x += y.x; Vy.y += y.y;
        Vz.x  = fmaf(x.x, x.x, Vz.x);  Vz.x  = fmaf(y.x, y.x, Vz.x);
        Vz.y  = fmaf(x.y, x.y, Vz.y);  Vz.y  = fmaf(y.y, y.y, Vz.y);
        Vxy.x = fmaf(x.x, y.x, Vxy.x);
        Vxy.y = fmaf(x.y, y.y, Vxy.y);
    }
    // nx/ny hold row 7. Scalar prefetch pointers for row 8+, clamped.
    const int r8 = min(oy0 + 8, H - 1) - oy0;
    const float* fx = px + r8 * W;
    const float* fy = py + r8 * W;
    int rabs = oy0 + 8;

    float acc = 0.f;

    #pragma unroll 1
    for (int g = 0; g < 3; ++g) {
        if (oy0 + 7 * g >= OHT) break;     // scalar early-exit (last chunk)
        #pragma unroll
        for (int i = 0; i < 7; ++i) {      // t = 7g+i, ring slot i (static)
            const int t = g * 7 + i;
            // ---- emit output row oy0+t: shared-ladder h-pairs, 2 cols/lane ----
            {
                float2 hx = hpair(Vx);
                float2 hy = hpair(Vy);
                float2 hz = hpair(Vz);
                float2 hw = hpair(Vxy);
                float ve = ssim_v(hx.x, hy.x, hz.x, hw.x);
                float vo = ssim_v(hx.y, hy.y, hz.y, hw.y);
                bool rok = (oy0 + t) < OHT;          // scalar
                acc += (oke && rok) ? ve : 0.f;
                acc += (oko && rok) ? vo : 0.f;
            }
            // ---- advance: consume prefetched row t+7, prefetch row t+8 ----
            {
                float2 xo = ringx[i], yo = ringy[i];
                float2 xn, yn;
                xn.x = clip01(nx.x); xn.y = clip01(nx.y);
                yn.x = clip01(ny.x); yn.y = clip01(ny.y);
                nx = *(const float2*)(fx + co);
                ny = *(const float2*)(fy + co);
                if (rabs < H - 1) { fx += W; fy += W; }  // scalar guard
                ++rabs;
                Vx.x += xn.x - xo.x;  Vx.y += xn.y - xo.y;
                Vy.x += yn.x - yo.x;  Vy.y += yn.y - yo.y;
                float zne = fmaf(xn.x, xn.x, yn.x * yn.x);
                float zoe = fmaf(xo.x, xo.x, yo.x * yo.x);
                float zno = fmaf(xn.y, xn.y, yn.y * yn.y);
                float zoo = fmaf(xo.y, xo.y, yo.y * yo.y);
                Vz.x += zne - zoe;    Vz.y += zno - zoo;
                Vxy.x += fmaf(xn.x, yn.x, -(xo.x * yo.x));
                Vxy.y += fmaf(xn.y, yn.y, -(xo.y * yo.y));
                ringx[i] = xn; ringy[i] = yn;
            }
        }
    }

    // ---- wave reduction, one partial per wave ----
    #pragma unroll
    for (int off = 32; off >= 1; off >>= 1)
        acc += __shfl_down(acc, off, 64);
    if (lane == 0) {
        if (partial) partial[wid] = acc;
        else atomicAdd(out_atomic, acc);
    }
}

__global__ __launch_bounds__(256)
void ssim_finish(const float* __restrict__ partial, float* __restrict__ out)
{
    __shared__ float red[4];
    float s = 0.f;
    for (int i = threadIdx.x; i < NWAVE; i += 256) s += partial[i];
    #pragma unroll
    for (int off = 32; off >= 1; off >>= 1)
        s += __shfl_down(s, off, 64);
    if ((threadIdx.x & 63) == 0) red[threadIdx.x >> 6] = s;
    __syncthreads();
    if (threadIdx.x == 0) {
        float t = red[0] + red[1] + red[2] + red[3];
        out[0] = 1.0f - t / NPIX;
    }
}

__global__ void ssim_zero(float* out) { out[0] = 0.0f; }
__global__ void ssim_finish_atomic(float* out) { out[0] = 1.0f - out[0] / NPIX; }

extern "C" void kernel_launch(void* const* d_in, const int* in_sizes, int n_in,
                              void* d_out, int out_size, void* d_ws, size_t ws_size,
                              hipStream_t stream) {
    const float* pred = (const float*)d_in[0];
    const float* targ = (const float*)d_in[1];
    float* out = (float*)d_out;

    dim3 block(256);
    dim3 grid(NWAVE / 4);   // 1500 blocks, 4 waves each

    if (ws_size >= (size_t)NWAVE * sizeof(float)) {
        float* part = (float*)d_ws;
        ssim_stream<<<grid, block, 0, stream>>>(pred, targ, part, nullptr);
        ssim_finish<<<1, 256, 0, stream>>>(part, out);
    } else {
        ssim_zero<<<1, 1, 0, stream>>>(out);
        ssim_stream<<<grid, block, 0, stream>>>(pred, targ, nullptr, out);
        ssim_finish_atomic<<<1, 1, 0, stream>>>(out);
    }
}

// Round 17
// 35.048 us; speedup vs baseline: 1.4689x; 1.0916x over previous
//
#include <hip/hip_runtime.h>

typedef float v2 __attribute__((ext_vector_type(2)));

#define W 512
#define H 512
#define OWID 506
#define OHT 506
#define BC 48              // 16 images * 3 channels
#define SEGOUT 26          // valid output cols per 16-lane segment (2/lane, q<=12)
#define WAVEOUT 104        // 4 segments
#define NSTRIP 5           // 5*104 = 520 >= 506
#define CH 21              // output rows per chunk (3 groups of 7)
#define NCHUNK 25          // 25*21 = 525 >= 506
#define NWAVE (BC*NSTRIP*NCHUNK)   // 6000, divisible by 4
#define NWG   (NWAVE/4)            // 1500 blocks
#define NPIX 12289728.0f           // 16*3*506*506

__device__ __forceinline__ v2 clip2(v2 v) {
    const v2 z = {0.f, 0.f}, o = {1.f, 1.f};
    return __builtin_elementwise_min(__builtin_elementwise_max(v, z), o);
}

// DPP row_shl:N — lane p receives lane p+N within its 16-lane row; 0 if OOB.
template <int N>
__device__ __forceinline__ float dpp_shl(float v) {
    int r = __builtin_amdgcn_update_dpp(0, __float_as_int(v),
                                        0x100 + N, 0xF, 0xF, true);
    return __int_as_float(r);
}

// V = (even-col sum, odd-col sum). Returns (h for col 2q, h for col 2q+1).
__device__ __forceinline__ v2 hpair(v2 V) {
    float P  = V.x + V.y;
    float S2 = P + dpp_shl<1>(P);
    float S4 = S2 + dpp_shl<2>(S2);
    v2 h;
    h.x = S4 - dpp_shl<3>(V.y);
    h.y = S4 - V.x;
    return h;
}

// sum-domain SSIM (scaled by 49^4), packed over (even,odd) columns
__device__ __forceinline__ v2 ssim2(v2 a0, v2 a1, v2 az, v2 a4) {
    const v2 c1p  = {0.2401f, 0.2401f};          // C1 * 49^2
    const v2 c2p  = {2.1609f, 2.1609f};          // C2 * 49^2
    const v2 cvn  = {49.f/48.f, 49.f/48.f};
    const v2 cvn2 = {49.f/24.f, 49.f/24.f};
    const v2 k49  = {49.f, 49.f};
    const v2 k2   = {2.f, 2.f};
    v2 t01  = a0 * a1;
    v2 qs   = __builtin_elementwise_fma(a0, a0, a1 * a1);
    v2 w4   = __builtin_elementwise_fma(k49, a4, -t01);
    v2 num1 = __builtin_elementwise_fma(k2, t01, c1p);
    v2 num2 = __builtin_elementwise_fma(cvn2, w4, c2p);
    v2 w23  = __builtin_elementwise_fma(k49, az, -qs);
    v2 den1 = qs + c1p;
    v2 den2 = __builtin_elementwise_fma(cvn, w23, c2p);
    v2 num = num1 * num2;
    v2 den = den1 * den2;
    v2 r;
    r.x = __builtin_amdgcn_rcpf(den.x);
    r.y = __builtin_amdgcn_rcpf(den.y);
    return num * r;
}

__global__ __launch_bounds__(256)
void ssim_stream(const float* __restrict__ pred, const float* __restrict__ targ,
                 float* __restrict__ partial, float* __restrict__ out_atomic)
{
    // ---- bijective XCD swizzle (m204): contiguous wid span per XCD ----
    const int orig = blockIdx.x;
    const int xcd  = orig & 7, idx = orig >> 3;
    const int qq = NWG >> 3, rr = NWG & 7;     // 187, 4
    const int wg = (xcd < rr ? xcd * (qq + 1) : rr * (qq + 1) + (xcd - rr) * qq) + idx;

    const int wid  = __builtin_amdgcn_readfirstlane(wg * 4 + (threadIdx.x >> 6));
    const int lane = threadIdx.x & 63;
    const int seg  = lane >> 4;
    const int q    = lane & 15;

    // STRIP-FASTEST decomposition (R16): co-dispatched waves = 5 strips of the
    // same (image, row-chunk) -> contiguous 2KB device-wide row reads.
    const int bc    = wid / (NSTRIP * NCHUNK);
    const int rem   = wid - bc * (NSTRIP * NCHUNK);
    const int chunk = rem / NSTRIP;
    const int strip = rem - chunk * NSTRIP;

    const int ce = strip * WAVEOUT + seg * SEGOUT + 2 * q;  // even col this lane owns
    const int co = min(ce, W - 2);                          // clamped v2 col
    const bool oke = (q <= 12) && (ce     < OWID);
    const bool oko = (q <= 12) && (ce + 1 < OWID);

    const int oy0 = chunk * CH;
    const size_t base = (size_t)bc * (H * W) + (size_t)oy0 * W;
    const float* __restrict__ px = pred + base;   // scalar base, row oy0
    const float* __restrict__ py = targ + base;

    // ---- vertical-first state: ring of clipped pairs, running pair sums ----
    v2 ringx[7], ringy[7];
    v2 Vx = {0,0}, Vy = {0,0}, Vz = {0,0}, Vxy = {0,0};

    v2 nx = *(const v2*)(px + co);
    v2 ny = *(const v2*)(py + co);
    #pragma unroll
    for (int i = 0; i < 7; ++i) {
        v2 xr = nx, yr = ny;
        nx = *(const v2*)(px + (i + 1) * W + co);   // rows 1..7 (<=511)
        ny = *(const v2*)(py + (i + 1) * W + co);
        v2 x = clip2(xr), y = clip2(yr);
        ringx[i] = x; ringy[i] = y;
        Vx += x;
        Vy += y;
        Vz  += __builtin_elementwise_fma(x, x, y * y);
        Vxy += x * y;
    }
    // nx/ny hold row 7. Scalar prefetch pointers for row 8+, clamped.
    const int r8 = min(oy0 + 8, H - 1) - oy0;
    const float* fx = px + r8 * W;
    const float* fy = py + r8 * W;
    int rabs = oy0 + 8;

    float acc = 0.f;

    #pragma unroll 1
    for (int g = 0; g < 3; ++g) {
        if (oy0 + 7 * g >= OHT) break;     // scalar early-exit (last chunk)
        #pragma unroll
        for (int i = 0; i < 7; ++i) {      // t = 7g+i, ring slot i (static)
            const int t = g * 7 + i;
            // ---- emit output row oy0+t: shared-ladder h-pairs, packed SSIM ----
            {
                v2 hx = hpair(Vx);
                v2 hy = hpair(Vy);
                v2 hz = hpair(Vz);
                v2 hw = hpair(Vxy);
                v2 v = ssim2(hx, hy, hz, hw);
                bool rok = (oy0 + t) < OHT;          // scalar
                acc += (oke && rok) ? v.x : 0.f;
                acc += (oko && rok) ? v.y : 0.f;
            }
            // ---- advance: consume prefetched row t+7, prefetch row t+8 ----
            {
                v2 xo = ringx[i], yo = ringy[i];
                v2 xn = clip2(nx), yn = clip2(ny);
                nx = *(const v2*)(fx + co);
                ny = *(const v2*)(fy + co);
                if (rabs < H - 1) { fx += W; fy += W; }  // scalar guard
                ++rabs;
                Vx += xn - xo;
                Vy += yn - yo;
                v2 zn = __builtin_elementwise_fma(xn, xn, yn * yn);
                v2 zo = __builtin_elementwise_fma(xo, xo, yo * yo);
                Vz += zn - zo;
                Vxy += __builtin_elementwise_fma(xn, yn, -(xo * yo));
                ringx[i] = xn; ringy[i] = yn;
            }
        }
    }

    // ---- wave reduction, one partial per wave ----
    #pragma unroll
    for (int off = 32; off >= 1; off >>= 1)
        acc += __shfl_down(acc, off, 64);
    if (lane == 0) {
        if (partial) partial[wid] = acc;
        else atomicAdd(out_atomic, acc);
    }
}

__global__ __launch_bounds__(256)
void ssim_finish(const float* __restrict__ partial, float* __restrict__ out)
{
    __shared__ float red[4];
    float s = 0.f;
    for (int i = threadIdx.x; i < NWAVE; i += 256) s += partial[i];
    #pragma unroll
    for (int off = 32; off >= 1; off >>= 1)
        s += __shfl_down(s, off, 64);
    if ((threadIdx.x & 63) == 0) red[threadIdx.x >> 6] = s;
    __syncthreads();
    if (threadIdx.x == 0) {
        float t = red[0] + red[1] + red[2] + red[3];
        out[0] = 1.0f - t / NPIX;
    }
}

__global__ void ssim_zero(float* out) { out[0] = 0.0f; }
__global__ void ssim_finish_atomic(float* out) { out[0] = 1.0f - out[0] / NPIX; }

extern "C" void kernel_launch(void* const* d_in, const int* in_sizes, int n_in,
                              void* d_out, int out_size, void* d_ws, size_t ws_size,
                              hipStream_t stream) {
    const float* pred = (const float*)d_in[0];
    const float* targ = (const float*)d_in[1];
    float* out = (float*)d_out;

    dim3 block(256);
    dim3 grid(NWG);   // 1500 blocks, 4 waves each

    if (ws_size >= (size_t)NWAVE * sizeof(float)) {
        float* part = (float*)d_ws;
        ssim_stream<<<grid, block, 0, stream>>>(pred, targ, part, nullptr);
        ssim_finish<<<1, 256, 0, stream>>>(part, out);
    } else {
        ssim_zero<<<1, 1, 0, stream>>>(out);
        ssim_stream<<<grid, block, 0, stream>>>(pred, targ, nullptr, out);
        ssim_finish_atomic<<<1, 1, 0, stream>>>(out);
    }
}